// Round 8
// baseline (840.605 us; speedup 1.0000x reference)
//
#include <hip/hip_runtime.h>
#include <hip/hip_bf16.h>
#include <math.h>
#include <stdint.h>

// ---------------------------------------------------------------------------
// GCN 4-layer, mixed bf16/fp8 datapath:
//   h = relu( A_w @ (h @ W) + b ) x4, then log_softmax (fp32 out).
//   - dst-CSR built once per call; edges packed u32 (src<<15 | w*32767)
//   - CSR build is bucket-local (bucket = dst>>8). Launch graph (12 launches):
//       memset(bhist) -> [prep_weights ∥ bucket_hist] -> bucket_scan ->
//       [phaseA ∥ GEMM1] -> phaseB2 -> spmm1 -> gemm2 -> spmm2 -> gemm3 ->
//       spmm3 -> gemm4 -> spmm4.
//     The [A ∥ B] launches fuse independent kernels by blockIdx partition:
//     memory-bound scatter blocks overlap MFMA blocks in one dispatch
//     (multi-stream fork/join is unavailable under graph capture: no events).
//   - E2 staging is 4+1 B/edge: E2a u32 = src<<15|w15; E2b u8 = dst&255
//     (bucket id is positional). phaseB2's histogram pass reads only E2b
//     (3.2 MB, was 25.6), placement reads E2a+E2b.
//   - GEMM1/2: 128x128 tile, 4 waves x (4x4) 16x16x32 bf16 MFMA fragments,
//     BK=64, LDS 32KB; bijective XCD-chunk swizzle; GEMM1 reads fp32 X
//     directly (reg-stage + next-K-tile register prefetch under MFMA).
//   - All four supports stored fp8 e4m3 (HW cvt both ways): SpMM is
//     FETCH-bound at ~3.55 TB/s beyond-L2, so bytes == time.
//   - spmm_fp8<D,U,FINAL>: G=D/16 lanes/edge-group, 16B uintx4 gathers,
//     (64/G)*U edges in flight; HW v_cvt_pk_f32_fp8 decode; edge index
//     CLAMPED inside the row (cached re-read, no junk fetch); shfl_xor
//     butterfly merges groups; fused bias+relu (bf16 out) or, for FINAL
//     (L4), fused log_softmax over the 40 real classes (fp32 [n,40] out).
// ---------------------------------------------------------------------------

#define WAVE 64
#define NBK 512          // scatter buckets (dst >> 8); covers up to 131072 nodes
#define CHA 8192         // edges per histogram/phaseA block
typedef __attribute__((ext_vector_type(8))) short short8;
typedef __attribute__((ext_vector_type(8))) unsigned short ushort8;
typedef __attribute__((ext_vector_type(4))) unsigned int uintx4;
typedef __attribute__((ext_vector_type(4))) float floatx4;
typedef __attribute__((ext_vector_type(2))) float floatx2;

__device__ __forceinline__ void async_copy16(const void* g, void* l) {
    __builtin_amdgcn_global_load_lds(
        (const __attribute__((address_space(1))) void*)g,
        (__attribute__((address_space(3))) void*)l, 16, 0, 0);
}

// ---------------- fused: weight prep (bf16 transpose) ∥ bucket histogram ----
// blocks [0, nH): 512-bin LDS histogram of dst>>8 (CHA edges per block)
// blocks [nH, ..): weight transposes + bias pad
// Segments: Wt1 131072 | Wt2 32768 | Wt3 8192 | Wt4 4096 | b4p 64
__global__ __launch_bounds__(256) void prep_hist_kernel(
        const int* __restrict__ dst, int nE, int* __restrict__ bhist, int nH,
        const float* __restrict__ W1, const float* __restrict__ W2,
        const float* __restrict__ W3, const float* __restrict__ W4,
        const float* __restrict__ b4,
        __hip_bfloat16* __restrict__ Wt1, __hip_bfloat16* __restrict__ Wt2,
        __hip_bfloat16* __restrict__ Wt3, __hip_bfloat16* __restrict__ Wt4,
        float* __restrict__ b4p) {
    const int t = threadIdx.x;
    if ((int)blockIdx.x < nH) {
        __shared__ int h[NBK];
        const long e0 = (long)blockIdx.x * CHA;
        const int cnt = (int)((nE - e0 < CHA) ? (nE - e0) : CHA);
        for (int i = t; i < NBK; i += 256) h[i] = 0;
        __syncthreads();
        for (int i = t; i < cnt; i += 256)
            atomicAdd(&h[dst[e0 + i] >> 8], 1);
        __syncthreads();
        for (int i = t; i < NBK; i += 256)
            if (h[i]) atomicAdd(&bhist[i], h[i]);
        return;
    }
    int idx = ((int)blockIdx.x - nH) * 256 + t;
    if (idx < 131072) {                       // Wt1: K=512 N=256
        int n = idx >> 9, k = idx & 511;
        Wt1[idx] = __float2bfloat16(W1[(size_t)k * 256 + n]);
    } else if (idx < 131072 + 32768) {        // Wt2: K=256 N=128
        int l = idx - 131072;
        int n = l >> 8, k = l & 255;
        Wt2[l] = __float2bfloat16(W2[(size_t)k * 128 + n]);
    } else if (idx < 131072 + 32768 + 8192) { // Wt3: K=128 N=64
        int l = idx - 131072 - 32768;
        int n = l >> 7, k = l & 127;
        Wt3[l] = __float2bfloat16(W3[(size_t)k * 64 + n]);
    } else if (idx < 131072 + 32768 + 8192 + 4096) { // Wt4: K=64 N=40 pad 64
        int l = idx - 131072 - 32768 - 8192;
        int n = l >> 6, k = l & 63;
        float v = (n < 40) ? W4[(size_t)k * 40 + n] : 0.f;
        Wt4[l] = __float2bfloat16(v);
    } else if (idx < 131072 + 32768 + 8192 + 4096 + 64) {
        int l = idx - 131072 - 32768 - 8192 - 4096;
        b4p[l] = (l < 40) ? b4[l] : 0.f;
    }
}

// Exclusive scan of the 512 bucket counts -> bbase[513]; seeds phaseA cursors.
__global__ __launch_bounds__(512) void bucket_scan(const int* __restrict__ bhist,
                                                   int* __restrict__ bbase,
                                                   int* __restrict__ gcur) {
    __shared__ int sm[NBK];
    const int t = threadIdx.x;
    int x = bhist[t];
    sm[t] = x;
    __syncthreads();
    for (int off = 1; off < NBK; off <<= 1) {
        int add = (t >= off) ? sm[t - off] : 0;
        __syncthreads();
        if (t >= off) sm[t] += add;
        __syncthreads();
    }
    int excl = sm[t] - x;
    bbase[t] = excl;
    gcur[t] = excl;
    if (t == NBK - 1) bbase[NBK] = sm[t];
}

// ---------------- fused: phaseA scatter ∥ GEMM1 (fp32 A -> fp8 C) ----------
// blocks [0, nA): phaseA — bucket edges by dst>>8 into E2a/E2b staging via
//   per-block LDS histogram + one global reservation per (block,bucket).
// blocks [nA, ..): 128x128 bf16-MFMA GEMM, A = fp32 X reg-staged with
//   next-K-tile register prefetch; bijective XCD-chunk swizzle over the
//   gemm-local block index; fp8 e4m3 output (support for SpMM-L1).
__global__ __launch_bounds__(256) void phaseA_gemm1(
        const int* __restrict__ src, const int* __restrict__ dst,
        const float* __restrict__ ew, int nE, int* __restrict__ gcur,
        unsigned int* __restrict__ E2a, unsigned char* __restrict__ E2b,
        int nA,
        const float* __restrict__ X, const __hip_bfloat16* __restrict__ Wt,
        unsigned char* __restrict__ C, int M, int K, int Npitch) {
    __shared__ __align__(16) char smem[32768];
    const int t = threadIdx.x;

    if ((int)blockIdx.x < nA) {
        // ---- phaseA ----
        int* hist = (int*)smem;
        int* cur = hist + NBK;
        const long e0 = (long)blockIdx.x * CHA;
        const int cnt = (int)((nE - e0 < CHA) ? (nE - e0) : CHA);

        for (int i = t; i < NBK; i += 256) hist[i] = 0;
        __syncthreads();
        for (int i = t; i < cnt; i += 256)
            atomicAdd(&hist[dst[e0 + i] >> 8], 1);
        __syncthreads();
        for (int i = t; i < NBK; i += 256) {
            int h = hist[i];
            cur[i] = h ? atomicAdd(&gcur[i], h) : 0;   // global base, this block
        }
        __syncthreads();
        for (int i = t; i < cnt; i += 256) {
            int d = dst[e0 + i];
            unsigned int w15 = (unsigned int)(ew[e0 + i] * 32767.f + 0.5f);
            if (w15 > 32767u) w15 = 32767u;
            int pos = atomicAdd(&cur[d >> 8], 1);      // LDS atomic -> slot
            E2a[pos] = ((unsigned int)src[e0 + i] << 15) | w15;
            E2b[pos] = (unsigned char)(d & 255);
        }
        return;
    }

    // ---- GEMM1 ----
    __hip_bfloat16* sA = (__hip_bfloat16*)smem;            // 16 KB
    __hip_bfloat16* sB = (__hip_bfloat16*)(smem + 16384);  // 16 KB
    const int lane = t & 63;
    const int w = t >> 6;
    const int wy = w >> 1, wx = w & 1;
    const int quad = lane >> 4;
    const int l16 = lane & 15;

    // XCD-bijective swizzle over gemm-local flat id (hw xcd ~ flat%8; the
    // +nA offset is a constant mod-8 shift -> chunks still land per-XCD).
    const int ntx = Npitch >> 7;
    const int nty = (M + 127) >> 7;
    const int nwg = ntx * nty;
    const int flat = (int)blockIdx.x - nA;
    const int q = nwg >> 3, r = nwg & 7;
    const int xcd = flat & 7, pos = flat >> 3;
    const int logical = (xcd < r ? xcd * (q + 1) : r * (q + 1) + (xcd - r) * q) + pos;
    const int row0 = (logical / ntx) * 128;
    const int col0 = (logical % ntx) * 128;

    floatx4 acc[4][4];
#pragma unroll
    for (int mt = 0; mt < 4; mt++)
#pragma unroll
        for (int nt = 0; nt < 4; nt++) acc[mt][nt] = 0;

    const int arow = t >> 3;        // 0..31
    const int koff = (t & 7) * 8;

    float4 fa[4][2];                // fp32 A prefetch registers
    auto loadA = [&](int k0) {
#pragma unroll
        for (int rr = 0; rr < 4; rr++) {
            int gm = row0 + rr * 32 + arow;
            int gmc = (gm < M) ? gm : 0;
            const float* ap = X + (size_t)gmc * K + k0 + koff;
            fa[rr][0] = *(const float4*)ap;
            fa[rr][1] = *(const float4*)(ap + 4);
        }
    };
    loadA(0);

    for (int k0 = 0; k0 < K; k0 += 64) {
#pragma unroll
        for (int rr = 0; rr < 4; rr++) {
            int n = rr * 32 + arow;
            async_copy16(Wt + (size_t)(col0 + n) * K + k0 + koff,
                         (char*)sB + rr * 4096 + t * 16);
        }
#pragma unroll
        for (int rr = 0; rr < 4; rr++) {
            ushort8 pk;
#pragma unroll
            for (int i = 0; i < 4; i++) {
                __hip_bfloat16 b0 = __float2bfloat16(((const float*)&fa[rr][0])[i]);
                __hip_bfloat16 b1 = __float2bfloat16(((const float*)&fa[rr][1])[i]);
                pk[i] = *(unsigned short*)&b0;
                pk[4 + i] = *(unsigned short*)&b1;
            }
            *(ushort8*)((char*)sA + rr * 4096 + t * 16) = pk;
        }
        __syncthreads();

        if (k0 + 64 < K) loadA(k0 + 64);   // in flight across MFMA cluster

        short8 af[4][2], bfr[4][2];
#pragma unroll
        for (int mt = 0; mt < 4; mt++)
#pragma unroll
            for (int kk = 0; kk < 2; kk++)
                af[mt][kk] = *(const short8*)((const char*)sA +
                             (wy * 64 + mt * 16 + l16) * 128 + kk * 64 + quad * 16);
#pragma unroll
        for (int nt = 0; nt < 4; nt++)
#pragma unroll
            for (int kk = 0; kk < 2; kk++)
                bfr[nt][kk] = *(const short8*)((const char*)sB +
                              (wx * 64 + nt * 16 + l16) * 128 + kk * 64 + quad * 16);
#pragma unroll
        for (int kk = 0; kk < 2; kk++)
#pragma unroll
            for (int mt = 0; mt < 4; mt++)
#pragma unroll
                for (int nt = 0; nt < 4; nt++)
                    acc[mt][nt] = __builtin_amdgcn_mfma_f32_16x16x32_bf16(
                        af[mt][kk], bfr[nt][kk], acc[mt][nt], 0, 0, 0);
        __syncthreads();
    }

#pragma unroll
    for (int mt = 0; mt < 4; mt++) {
#pragma unroll
        for (int nt = 0; nt < 4; nt++) {
            int gn = col0 + wx * 64 + nt * 16 + l16;
            int gmb = row0 + wy * 64 + mt * 16 + quad * 4;
#pragma unroll
            for (int rr = 0; rr < 4; rr++) {
                int gm = gmb + rr;
                if (gm < M) {
                    float v = acc[mt][nt][rr];
                    int p = __builtin_amdgcn_cvt_pk_fp8_f32(v, v, 0, false);
                    C[(size_t)gm * Npitch + gn] = (unsigned char)(p & 0xff);
                }
            }
        }
    }
}

// Phase B2: one block per bucket. Histogram pass reads only E2b (1B/edge);
// placement reads E2a+E2b; LDS-only cursors; writes row_ptr + exact CSR.
__global__ __launch_bounds__(256) void scatter_phaseB2(const unsigned int* __restrict__ E2a,
                                                       const unsigned char* __restrict__ E2b,
                                                       const int* __restrict__ bbase,
                                                       int n_nodes, int nE,
                                                       int* __restrict__ row_ptr,
                                                       unsigned int* __restrict__ edge_pk) {
    __shared__ int cnt[256];
    __shared__ int pfx[256];
    __shared__ int cur[256];
    const int b = blockIdx.x;
    const int t = threadIdx.x;
    const int s = bbase[b];
    const int e = bbase[b + 1];

    cnt[t] = 0;
    __syncthreads();
    for (int i = s + t; i < e; i += 256)
        atomicAdd(&cnt[E2b[i]], 1);
    __syncthreads();
    pfx[t] = cnt[t];
    __syncthreads();
    for (int off = 1; off < 256; off <<= 1) {
        int add = (t >= off) ? pfx[t - off] : 0;
        __syncthreads();
        if (t >= off) pfx[t] += add;
        __syncthreads();
    }
    const int excl = pfx[t] - cnt[t];
    const int node = b * 256 + t;
    if (node < n_nodes) row_ptr[node] = s + excl;
    if (b == 0 && t == 0) row_ptr[n_nodes] = nE;
    cur[t] = s + excl;
    __syncthreads();
    for (int i = s + t; i < e; i += 256) {
        int p = atomicAdd(&cur[E2b[i]], 1);    // LDS atomic
        edge_pk[p] = E2a[i];
    }
}

// ---------------- 128x128 MFMA GEMM (bf16 A, standalone; GEMM2) -------------
// OUTM: 0 = bf16 output, 1 = fp8 e4m3 output (HW cvt_pk_fp8_f32).

template <int OUTM>
__global__ __launch_bounds__(256) void gemm128(const __hip_bfloat16* __restrict__ A,
                                               const __hip_bfloat16* __restrict__ Wt,
                                               void* __restrict__ C,
                                               int M, int K, int Npitch) {
    __shared__ __align__(16) __hip_bfloat16 sA[128 * 64];
    __shared__ __align__(16) __hip_bfloat16 sB[128 * 64];
    const int t = threadIdx.x;
    const int lane = t & 63;
    const int w = t >> 6;
    const int wy = w >> 1, wx = w & 1;
    const int quad = lane >> 4;
    const int l16 = lane & 15;

    const int nwg = (int)(gridDim.x * gridDim.y);
    const int flat = (int)(blockIdx.y * gridDim.x + blockIdx.x);
    const int q = nwg >> 3, r = nwg & 7;
    const int xcd = flat & 7, pos = flat >> 3;
    const int logical = (xcd < r ? xcd * (q + 1) : r * (q + 1) + (xcd - r) * q) + pos;
    const int row0 = (logical / (int)gridDim.x) * 128;
    const int col0 = (logical % (int)gridDim.x) * 128;

    floatx4 acc[4][4];
#pragma unroll
    for (int mt = 0; mt < 4; mt++)
#pragma unroll
        for (int nt = 0; nt < 4; nt++) acc[mt][nt] = 0;

    const int arow = t >> 3;
    const int koff = (t & 7) * 8;

    for (int k0 = 0; k0 < K; k0 += 64) {
#pragma unroll
        for (int rr = 0; rr < 4; rr++) {
            int n = rr * 32 + arow;
            async_copy16(Wt + (size_t)(col0 + n) * K + k0 + koff,
                         (char*)sB + rr * 4096 + t * 16);
        }
#pragma unroll
        for (int rr = 0; rr < 4; rr++) {
            int gm = row0 + rr * 32 + arow;
            int gmc = (gm < M) ? gm : 0;
            async_copy16(A + (size_t)gmc * K + k0 + koff,
                         (char*)sA + rr * 4096 + t * 16);
        }
        __syncthreads();

        short8 af[4][2], bfr[4][2];
#pragma unroll
        for (int mt = 0; mt < 4; mt++)
#pragma unroll
            for (int kk = 0; kk < 2; kk++)
                af[mt][kk] = *(const short8*)((const char*)sA +
                             (wy * 64 + mt * 16 + l16) * 128 + kk * 64 + quad * 16);
#pragma unroll
        for (int nt = 0; nt < 4; nt++)
#pragma unroll
            for (int kk = 0; kk < 2; kk++)
                bfr[nt][kk] = *(const short8*)((const char*)sB +
                              (wx * 64 + nt * 16 + l16) * 128 + kk * 64 + quad * 16);
#pragma unroll
        for (int kk = 0; kk < 2; kk++)
#pragma unroll
            for (int mt = 0; mt < 4; mt++)
#pragma unroll
                for (int nt = 0; nt < 4; nt++)
                    acc[mt][nt] = __builtin_amdgcn_mfma_f32_16x16x32_bf16(
                        af[mt][kk], bfr[nt][kk], acc[mt][nt], 0, 0, 0);
        __syncthreads();
    }

#pragma unroll
    for (int mt = 0; mt < 4; mt++) {
#pragma unroll
        for (int nt = 0; nt < 4; nt++) {
            int gn = col0 + wx * 64 + nt * 16 + l16;
            int gmb = row0 + wy * 64 + mt * 16 + quad * 4;
#pragma unroll
            for (int rr = 0; rr < 4; rr++) {
                int gm = gmb + rr;
                if (gm < M) {
                    if (OUTM == 0) {
                        ((__hip_bfloat16*)C)[(size_t)gm * Npitch + gn] =
                            __float2bfloat16(acc[mt][nt][rr]);
                    } else {
                        float v = acc[mt][nt][rr];
                        int p = __builtin_amdgcn_cvt_pk_fp8_f32(v, v, 0, false);
                        ((unsigned char*)C)[(size_t)gm * Npitch + gn] =
                            (unsigned char)(p & 0xff);
                    }
                }
            }
        }
    }
}

// ---------------- 128x64 MFMA GEMM (N=64 layers), bf16 A --------------------

template <int OUTM>
__global__ __launch_bounds__(256) void gemm_bf16(const __hip_bfloat16* __restrict__ A,
                                                 const __hip_bfloat16* __restrict__ Wt,
                                                 void* __restrict__ C,
                                                 int M, int K, int Npitch) {
    __shared__ __align__(16) __hip_bfloat16 sA[128 * 64];
    __shared__ __align__(16) __hip_bfloat16 sB[64 * 64];
    const int t = threadIdx.x;
    const int lane = t & 63;
    const int w = t >> 6;
    const int wy = w >> 1, wx = w & 1;
    const int quad = lane >> 4;
    const int l16 = lane & 15;
    const int row0 = blockIdx.y * 128;
    const int col0 = blockIdx.x * 64;

    floatx4 acc[4][2];
#pragma unroll
    for (int mt = 0; mt < 4; mt++)
#pragma unroll
        for (int nt = 0; nt < 2; nt++) acc[mt][nt] = 0;

    const int arow = t >> 3;
    const int koff = (t & 7) * 8;

    for (int k0 = 0; k0 < K; k0 += 64) {
#pragma unroll
        for (int r = 0; r < 4; r++) {
            int gm = row0 + r * 32 + arow;
            int gmc = (gm < M) ? gm : 0;
            async_copy16(A + (size_t)gmc * K + k0 + koff,
                         (char*)sA + r * 4096 + t * 16);
        }
#pragma unroll
        for (int r = 0; r < 2; r++) {
            int n = r * 32 + arow;
            async_copy16(Wt + (size_t)(col0 + n) * K + k0 + koff,
                         (char*)sB + r * 4096 + t * 16);
        }
        __syncthreads();

        short8 af[4][2], bfr[2][2];
#pragma unroll
        for (int mt = 0; mt < 4; mt++)
#pragma unroll
            for (int kk = 0; kk < 2; kk++)
                af[mt][kk] = *(const short8*)((const char*)sA +
                             (wy * 64 + mt * 16 + l16) * 128 + kk * 64 + quad * 16);
#pragma unroll
        for (int nt = 0; nt < 2; nt++)
#pragma unroll
            for (int kk = 0; kk < 2; kk++)
                bfr[nt][kk] = *(const short8*)((const char*)sB +
                              (wx * 32 + nt * 16 + l16) * 128 + kk * 64 + quad * 16);
#pragma unroll
        for (int kk = 0; kk < 2; kk++)
#pragma unroll
            for (int mt = 0; mt < 4; mt++)
#pragma unroll
                for (int nt = 0; nt < 2; nt++)
                    acc[mt][nt] = __builtin_amdgcn_mfma_f32_16x16x32_bf16(
                        af[mt][kk], bfr[nt][kk], acc[mt][nt], 0, 0, 0);
        __syncthreads();
    }

#pragma unroll
    for (int mt = 0; mt < 4; mt++) {
#pragma unroll
        for (int nt = 0; nt < 2; nt++) {
            int gn = col0 + wx * 32 + nt * 16 + l16;
            int gmb = row0 + wy * 64 + mt * 16 + quad * 4;
#pragma unroll
            for (int r = 0; r < 4; r++) {
                int gm = gmb + r;
                if (gm < M) {
                    if (OUTM == 0) {
                        ((__hip_bfloat16*)C)[(size_t)gm * Npitch + gn] =
                            __float2bfloat16(acc[mt][nt][r]);
                    } else {
                        float v = acc[mt][nt][r];
                        int p = __builtin_amdgcn_cvt_pk_fp8_f32(v, v, 0, false);
                        ((unsigned char*)C)[(size_t)gm * Npitch + gn] =
                            (unsigned char)(p & 0xff);
                    }
                }
            }
        }
    }
}

// ---------------- SpMM, fp8 support (D cols), bias+relu / final softmax ----

template <int D, int U, bool FINAL>
__global__ __launch_bounds__(256) void spmm_fp8(const int* __restrict__ row_ptr,
                                                const unsigned int* __restrict__ edge_pk,
                                                const unsigned char* __restrict__ sup8,
                                                const float* __restrict__ bias,
                                                void* __restrict__ out,
                                                int n_nodes) {
    constexpr int G = D / 16;            // lanes per edge-group
    constexpr int NG = 64 / G;           // edge groups per wave
    constexpr int CH = NG * U;           // edges consumed per iteration
    int node = blockIdx.x * (256 / WAVE) + (threadIdx.x >> 6);
    if (node >= n_nodes) return;
    node = __builtin_amdgcn_readfirstlane(node);
    const int lane = threadIdx.x & 63;
    const int g = lane / G;              // edge-group id
    const int t = lane & (G - 1);        // owns cols [t*16, t*16+16)
    int e = row_ptr[node];
    const int end = row_ptr[node + 1];
    const unsigned char* sup = sup8 + t * 16;

    float acc[16];
#pragma unroll
    for (int i = 0; i < 16; i++) acc[i] = 0.f;

    while (e < end) {
        const int base = e + g * U;
        unsigned int pk[U];
#pragma unroll
        for (int u = 0; u < U; u++) {
            int idx = base + u;
            if (idx > end - 1) idx = end - 1;   // clamp INSIDE row
            pk[u] = edge_pk[idx];
        }
        uintx4 v[U];
#pragma unroll
        for (int u = 0; u < U; u++)
            v[u] = *(const uintx4*)(sup + (size_t)(pk[u] >> 15) * D);
#pragma unroll
        for (int u = 0; u < U; u++) {
            float wq = (float)(pk[u] & 0x7fffu) * (1.f / 32767.f);
            float wt = (base + u < end) ? wq : 0.f;
#pragma unroll
            for (int d = 0; d < 4; d++) {
                floatx2 lo = __builtin_amdgcn_cvt_pk_f32_fp8(v[u][d], false);
                floatx2 hi = __builtin_amdgcn_cvt_pk_f32_fp8(v[u][d], true);
                acc[d * 4 + 0] += lo[0] * wt;
                acc[d * 4 + 1] += lo[1] * wt;
                acc[d * 4 + 2] += hi[0] * wt;
                acc[d * 4 + 3] += hi[1] * wt;
            }
        }
        e += CH;
    }

#pragma unroll
    for (int off = G; off < 64; off <<= 1)
#pragma unroll
        for (int i = 0; i < 16; i++) acc[i] += __shfl_xor(acc[i], off);

    if (!FINAL) {
        if (lane < G) {
            ushort8 o0, o1;
#pragma unroll
            for (int i = 0; i < 8; i++) {
                float r0 = acc[i] + bias[t * 16 + i];
                float r1 = acc[8 + i] + bias[t * 16 + 8 + i];
                r0 = r0 > 0.f ? r0 : 0.f;
                r1 = r1 > 0.f ? r1 : 0.f;
                __hip_bfloat16 b0 = __float2bfloat16(r0);
                __hip_bfloat16 b1 = __float2bfloat16(r1);
                o0[i] = *(unsigned short*)&b0;
                o1[i] = *(unsigned short*)&b1;
            }
            union { ushort8 s; uintx4 u; } c0, c1; c0.s = o0; c1.s = o1;
            unsigned short* op = (unsigned short*)out + (size_t)node * D + t * 16;
            __builtin_nontemporal_store(c0.u, (uintx4*)op);
            __builtin_nontemporal_store(c1.u, (uintx4*)(op + 8));
        }
    } else {
        float r[16];
#pragma unroll
        for (int i = 0; i < 16; i++) {
            float x = acc[i] + bias[t * 16 + i];
            r[i] = x > 0.f ? x : 0.f;
        }
        float m = -INFINITY;
#pragma unroll
        for (int i = 0; i < 16; i++)
            if (t * 16 + i < 40) m = fmaxf(m, r[i]);
#pragma unroll
        for (int off = 1; off < G; off <<= 1) m = fmaxf(m, __shfl_xor(m, off));
        float s = 0.f;
#pragma unroll
        for (int i = 0; i < 16; i++)
            if (t * 16 + i < 40) s += __expf(r[i] - m);
#pragma unroll
        for (int off = 1; off < G; off <<= 1) s += __shfl_xor(s, off);
        const float lse = __logf(s);
        if (lane < G) {
            float* op = (float*)out + (size_t)node * 40;
#pragma unroll
            for (int i = 0; i < 16; i++) {
                int c = t * 16 + i;
                if (c < 40) op[c] = r[i] - m - lse;
            }
        }
    }
}

// ---------------- launch ----------------------------------------------------

extern "C" void kernel_launch(void* const* d_in, const int* in_sizes, int n_in,
                              void* d_out, int out_size, void* d_ws, size_t ws_size,
                              hipStream_t stream) {
    const float* x    = (const float*)d_in[0];
    const int*   esrc = (const int*)d_in[1];
    const int*   edst = (const int*)d_in[2];
    const float* ew   = (const float*)d_in[3];
    const float* Wm[4] = {(const float*)d_in[4], (const float*)d_in[6],
                          (const float*)d_in[8], (const float*)d_in[10]};
    const float* bm[4] = {(const float*)d_in[5], (const float*)d_in[7],
                          (const float*)d_in[9], (const float*)d_in[11]};
    const int NFEAT = 512;
    const int n_nodes = in_sizes[0] / NFEAT;
    const int n_edges = in_sizes[1];
    float* out = (float*)d_out;

    // --- workspace carve ---
    char* wsp = (char*)d_ws;
    size_t off = 0;
    auto alloc = [&](size_t bytes) -> void* {
        void* p = wsp + off;
        off += (bytes + 255) & ~(size_t)255;
        return p;
    };
    __hip_bfloat16* Sb = (__hip_bfloat16*)alloc((size_t)n_nodes * 256 * sizeof(__hip_bfloat16));
    __hip_bfloat16* Hb = (__hip_bfloat16*)alloc((size_t)n_nodes * 256 * sizeof(__hip_bfloat16));
    __hip_bfloat16* Wt1 = (__hip_bfloat16*)alloc(256 * 512 * sizeof(__hip_bfloat16));
    __hip_bfloat16* Wt2 = (__hip_bfloat16*)alloc(128 * 256 * sizeof(__hip_bfloat16));
    __hip_bfloat16* Wt3 = (__hip_bfloat16*)alloc(64 * 128 * sizeof(__hip_bfloat16));
    __hip_bfloat16* Wt4 = (__hip_bfloat16*)alloc(64 * 64 * sizeof(__hip_bfloat16));
    float* b4p     = (float*)alloc(64 * sizeof(float));
    int*   row_ptr = (int*)alloc(((size_t)n_nodes + 1) * sizeof(int));
    int*   bhist   = (int*)alloc(NBK * sizeof(int));
    int*   bbase   = (int*)alloc((NBK + 1) * sizeof(int));
    int*   gcur    = (int*)alloc(NBK * sizeof(int));
    unsigned int*  edge_pk = (unsigned int*)alloc((size_t)n_edges * sizeof(unsigned int));
    unsigned char* E2b     = (unsigned char*)alloc((size_t)n_edges);
    // E2a (4B/edge) aliases Hb (first written by L1 SpMM, after phaseB2) -> safe.
    unsigned int* E2a = (unsigned int*)Hb;
    // fp8 supports alias Sb (GEMM writes fp8, spmm reads it, next GEMM
    // overwrites the same region -> sequential, safe).
    unsigned char* Sb8 = (unsigned char*)Sb;
    (void)ws_size;

    const int nH = (n_edges + CHA - 1) / CHA;              // hist/phaseA blocks
    const int nPrep = (131072 + 32768 + 8192 + 4096 + 64 + 255) / 256;

    // --- CSR build front-end (hist fused with weight prep) ---
    hipMemsetAsync(bhist, 0, NBK * sizeof(int), stream);
    prep_hist_kernel<<<nH + nPrep, 256, 0, stream>>>(
        edst, n_edges, bhist, nH,
        Wm[0], Wm[1], Wm[2], Wm[3], bm[3], Wt1, Wt2, Wt3, Wt4, b4p);
    bucket_scan<<<1, NBK, 0, stream>>>(bhist, bbase, gcur);

    // --- phaseA scatter fused with GEMM1 (independent; mem-bound ∥ MFMA) ---
    const int nty = (n_nodes + 127) / 128;
    phaseA_gemm1<<<nH + 2 * nty, 256, 0, stream>>>(
        esrc, edst, ew, n_edges, gcur, E2a, E2b, nH,
        x, Wt1, Sb8, n_nodes, 512, 256);
    scatter_phaseB2<<<NBK, 256, 0, stream>>>(E2a, E2b, bbase, n_nodes, n_edges,
                                             row_ptr, edge_pk);

    // --- layers ---
    int spmm_blocks = (n_nodes + 3) / 4;
    dim3 gg2(1, nty);                             // 128x128 tiles (N=128)
    dim3 g3(1, nty);                              // 128x64 tiles (N=64)

    // L1 SpMM (support fp8, written by fused GEMM1)
    spmm_fp8<256, 4, false><<<spmm_blocks, 256, 0, stream>>>(
        row_ptr, edge_pk, Sb8, bm[0], Hb, n_nodes);
    // L2: 256 -> 128 (support fp8 e4m3)
    gemm128<1><<<gg2, 256, 0, stream>>>(Hb, Wt2, Sb8, n_nodes, 256, 128);
    spmm_fp8<128, 2, false><<<spmm_blocks, 256, 0, stream>>>(
        row_ptr, edge_pk, Sb8, bm[1], Hb, n_nodes);
    // L3: 128 -> 64 (support fp8 e4m3)
    gemm_bf16<1><<<g3, 256, 0, stream>>>(Hb, Wt3, Sb8, n_nodes, 128, 64);
    spmm_fp8<64, 1, false><<<spmm_blocks, 256, 0, stream>>>(
        row_ptr, edge_pk, Sb8, bm[2], Hb, n_nodes);
    // L4: 64 -> 40 (N padded to 64; support fp8; fused log_softmax)
    gemm_bf16<1><<<g3, 256, 0, stream>>>(Hb, Wt4, Sb8, n_nodes, 64, 64);
    spmm_fp8<64, 1, true><<<spmm_blocks, 256, 0, stream>>>(
        row_ptr, edge_pk, Sb8, b4p, out, n_nodes);
}